// Round 11
// baseline (1901.206 us; speedup 1.0000x reference)
//
#include <hip/hip_runtime.h>
#include <math.h>

#define B_   256
#define S_   160
#define E_   300
#define H_   256
#define T_   200
#define G4H  1024
#define CH   16
#define NCH  10

typedef float  f32x4  __attribute__((ext_vector_type(4)));
typedef __bf16 bf16x4 __attribute__((ext_vector_type(4)));
typedef __bf16 bf16x8 __attribute__((ext_vector_type(8)));

__device__ __forceinline__ float sigf(float x) {
    float e = expf(-fabsf(x));
    float p = 1.0f / (1.0f + e);
    return x >= 0.0f ? p : e * p;
}

// permuted gate-col order: n' = (j>>4)*64 + g*16 + (j&15); orig row for n':
__device__ __forceinline__ int norig(int np) {
    return ((np >> 4) & 3) * 256 + ((np >> 6) << 4) + (np & 15);
}

// 4 consecutive K-values from concatenated [first(300) | second(200) | pad] row
__device__ __forceinline__ float4 pick4(const float* __restrict__ e,
                                        const float* __restrict__ k, int kg) {
    if (kg < E_)      return *(const float4*)(e + kg);
    if (kg < E_ + T_) return *(const float4*)(k + (kg - E_));
    return make_float4(0.f, 0.f, 0.f, 0.f);
}

__device__ __forceinline__ void split4(float4 v, bf16x4& h, bf16x4& l) {
    h[0] = (__bf16)v.x; l[0] = (__bf16)(v.x - (float)h[0]);
    h[1] = (__bf16)v.y; l[1] = (__bf16)(v.y - (float)h[1]);
    h[2] = (__bf16)v.z; l[2] = (__bf16)(v.z - (float)h[2]);
    h[3] = (__bf16)v.w; l[3] = (__bf16)(v.w - (float)h[3]);
}

// ---------------------------------------------------------------------------
// One-time weight prep: rows in permuted n' order, bf16 hi/lo planes.
// ---------------------------------------------------------------------------
__global__ __launch_bounds__(128) void prep_split(
    const float* __restrict__ Whh, const float* __restrict__ Wih,
    const float* __restrict__ Wkh,
    __bf16* __restrict__ whh_hi, __bf16* __restrict__ whh_lo,
    __bf16* __restrict__ wik_hi, __bf16* __restrict__ wik_lo)
{
    const int n  = blockIdx.x;                         // orig row: g*256 + j
    const int np = ((n & 255) >> 4) * 64 + (n >> 8) * 16 + (n & 15);
    const int t  = threadIdx.x;
    {
        const int k4 = t * 4;
        float4 v;
        if (k4 < E_)            v = *(const float4*)(Wih + (size_t)n * E_ + k4);
        else if (k4 < E_ + T_)  v = *(const float4*)(Wkh + (size_t)n * T_ + (k4 - E_));
        else                    v = make_float4(0.f, 0.f, 0.f, 0.f);
        bf16x4 h, l;
        split4(v, h, l);
        *(bf16x4*)(wik_hi + (size_t)np * 512 + k4) = h;
        *(bf16x4*)(wik_lo + (size_t)np * 512 + k4) = l;
    }
    if (t < 64) {
        const int k4 = t * 4;
        const float4 v = *(const float4*)(Whh + (size_t)n * 256 + k4);
        bf16x4 h, l;
        split4(v, h, l);
        *(bf16x4*)(whh_hi + (size_t)np * 256 + k4) = h;
        *(bf16x4*)(whh_lo + (size_t)np * 256 + k4) = l;
    }
}

// ---------------------------------------------------------------------------
// Input GEMM: split-bf16 MFMA, tile 128x128, BK=64 (8 k-iters: half the
// barriers, 2x MFMA/iter vs BK=32), 512 threads = 8 waves (wave tile 64x32).
// LDS 64KB, 2 blocks/CU. 8-chunk XOR swizzle pos = chunk ^ (row&7):
// ds_write_b128 and ds_read_b128 both <=2-way (free).
// ---------------------------------------------------------------------------
__global__ __launch_bounds__(512, 2) void gemm_g2(
    const int* __restrict__ x1, const int* __restrict__ x2,
    const float* __restrict__ key_c, const float* __restrict__ key_r,
    const float* __restrict__ emb,
    const __bf16* __restrict__ wik_hi, const __bf16* __restrict__ wik_lo,
    const float* __restrict__ bg,
    float* __restrict__ G, int s0)
{
    __shared__ __align__(16) __bf16 Ah[128 * 64];
    __shared__ __align__(16) __bf16 Al[128 * 64];
    __shared__ __align__(16) __bf16 Bh[128 * 64];
    __shared__ __align__(16) __bf16 Bl[128 * 64];

    const int t   = threadIdx.x;
    const int rnn = blockIdx.z;
    const int m0  = blockIdx.x * 128;
    const int n0  = blockIdx.y * 128;
    const int* xx = rnn ? x2 : x1;
    const float* key = rnn ? key_r : key_c;

    // staging: row r0 = t>>2 (0..127); thread owns chunks cq and cq+4 (8 bf16 each)
    const int r0 = t >> 2;
    const int cq = t & 3;
    const int p0 = (cq ^ (r0 & 7)) * 16;        // physical byte offset of chunk cq
    const int p1 = ((cq + 4) ^ (r0 & 7)) * 16;  // and of chunk cq+4

    const float* aeb; const float* akb;
    const __bf16* wph; const __bf16* wpl;
    {
        const int am = m0 + r0;
        const int bs = (am >> 4) * S_ + s0 + (am & 15);
        aeb = emb + (size_t)xx[bs] * E_;
        akb = key + (size_t)bs * T_;
        wph = wik_hi + (size_t)(n0 + r0) * 512;
        wpl = wik_lo + (size_t)(n0 + r0) * 512;
    }

    const int w  = t >> 6;       // 0..7
    const int wm = w >> 2;       // 0..1  (64-row half)
    const int wn = w & 3;        // 0..3  (32-col quarter)
    const int l  = t & 63;
    const int cl = l & 15;
    const int ch = l >> 4;

    f32x4 acc[4][2];
    #pragma unroll
    for (int fm = 0; fm < 4; ++fm)
        #pragma unroll
        for (int fn = 0; fn < 2; ++fn) acc[fm][fn] = (f32x4){0.f, 0.f, 0.f, 0.f};

    for (int kt = 0; kt < 8; ++kt) {
        const int kg0 = kt * 64 + cq * 8;        // chunk cq
        const int kg1 = kg0 + 32;                // chunk cq+4
        const float4 va0 = pick4(aeb, akb, kg0);
        const float4 va1 = pick4(aeb, akb, kg0 + 4);
        const float4 va2 = pick4(aeb, akb, kg1);
        const float4 va3 = pick4(aeb, akb, kg1 + 4);
        const bf16x8 vbh0 = *(const bf16x8*)(wph + kg0);
        const bf16x8 vbh1 = *(const bf16x8*)(wph + kg1);
        const bf16x8 vbl0 = *(const bf16x8*)(wpl + kg0);
        const bf16x8 vbl1 = *(const bf16x8*)(wpl + kg1);
        bf16x4 h0, l0, h1, l1, h2, l2, h3, l3;
        split4(va0, h0, l0); split4(va1, h1, l1);
        split4(va2, h2, l2); split4(va3, h3, l3);
        const bf16x8 sah0 = __builtin_shufflevector(h0, h1, 0, 1, 2, 3, 4, 5, 6, 7);
        const bf16x8 sal0 = __builtin_shufflevector(l0, l1, 0, 1, 2, 3, 4, 5, 6, 7);
        const bf16x8 sah1 = __builtin_shufflevector(h2, h3, 0, 1, 2, 3, 4, 5, 6, 7);
        const bf16x8 sal1 = __builtin_shufflevector(l2, l3, 0, 1, 2, 3, 4, 5, 6, 7);
        __syncthreads();
        {
            char* a = (char*)Ah + r0 * 128;
            char* b = (char*)Bh + r0 * 128;
            char* a2 = (char*)Al + r0 * 128;
            char* b2 = (char*)Bl + r0 * 128;
            *(bf16x8*)(a + p0)  = sah0;
            *(bf16x8*)(a + p1)  = sah1;
            *(bf16x8*)(a2 + p0) = sal0;
            *(bf16x8*)(a2 + p1) = sal1;
            *(bf16x8*)(b + p0)  = vbh0;
            *(bf16x8*)(b + p1)  = vbh1;
            *(bf16x8*)(b2 + p0) = vbl0;
            *(bf16x8*)(b2 + p1) = vbl1;
        }
        __syncthreads();

        #pragma unroll
        for (int s = 0; s < 2; ++s) {
            const int c = s * 4 + ch;           // logical chunk
            bf16x8 fBh[2], fBl[2];
            #pragma unroll
            for (int fn = 0; fn < 2; ++fn) {
                const int row = wn * 32 + fn * 16 + cl;
                const int off = row * 128 + (c ^ (row & 7)) * 16;
                fBh[fn] = *(const bf16x8*)((const char*)Bh + off);
                fBl[fn] = *(const bf16x8*)((const char*)Bl + off);
            }
            #pragma unroll
            for (int fm = 0; fm < 4; ++fm) {
                const int row = wm * 64 + fm * 16 + cl;
                const int off = row * 128 + (c ^ (row & 7)) * 16;
                const bf16x8 fAh = *(const bf16x8*)((const char*)Ah + off);
                const bf16x8 fAl = *(const bf16x8*)((const char*)Al + off);
                #pragma unroll
                for (int fn = 0; fn < 2; ++fn) {
                    acc[fm][fn] = __builtin_amdgcn_mfma_f32_16x16x32_bf16(fAh, fBh[fn], acc[fm][fn], 0, 0, 0);
                    acc[fm][fn] = __builtin_amdgcn_mfma_f32_16x16x32_bf16(fAh, fBl[fn], acc[fm][fn], 0, 0, 0);
                    acc[fm][fn] = __builtin_amdgcn_mfma_f32_16x16x32_bf16(fAl, fBh[fn], acc[fm][fn], 0, 0, 0);
                }
            }
        }
    }

    float bgl[2];
    #pragma unroll
    for (int fn = 0; fn < 2; ++fn)
        bgl[fn] = bg[norig(n0 + wn * 32 + fn * 16 + cl)];

    #pragma unroll
    for (int fm = 0; fm < 4; ++fm) {
        #pragma unroll
        for (int r = 0; r < 4; ++r) {
            const int m  = m0 + wm * 64 + fm * 16 + ch * 4 + r;
            const int b  = m >> 4;
            const int sl = m & 15;
            float* rowp = G + ((size_t)(rnn * CH + sl) * B_ + b) * G4H;
            #pragma unroll
            for (int fn = 0; fn < 2; ++fn)
                rowp[n0 + wn * 32 + fn * 16 + cl] = acc[fm][fn][r] + bgl[fn];
        }
    }
}

// ---------------------------------------------------------------------------
// One LSTM step, ZERO LDS / ZERO barriers. 512 one-wave blocks (64 thr).
// Wave tile: 16 m-rows x 64 n' (16 j x 4 gates) over full K=256: 96 MFMA as
// 4 independent gate chains. n' permutation makes the epilogue fully
// lane-local: lane (cl,ch) owns rows ch*4+r, col j=jt*16+cl, all 4 gates.
// A/B frags + G + c all issued from global at entry (W is L2-resident).
// ---------------------------------------------------------------------------
__global__ __launch_bounds__(64) void lstm_dir(
    const float* __restrict__ G,
    const __bf16* __restrict__ Whi, const __bf16* __restrict__ Wlo,
    const __bf16* __restrict__ hhi_in, const __bf16* __restrict__ hlo_in,
    __bf16* __restrict__ hhi_out, __bf16* __restrict__ hlo_out,
    float* __restrict__ cst, float* __restrict__ sc,
    int sl, int s_glob, int first)
{
    const int l  = threadIdx.x;
    const int cl = l & 15;
    const int ch = l >> 4;
    const int bid = blockIdx.x;
    const int mt  = bid >> 4;          // 0..31
    const int jt  = bid & 15;          // 0..15
    const int rnn = mt >> 4;
    const int b0  = (mt & 15) * 16;
    const int m0  = mt * 16;           // plane row base (= rnn*256 + b0)
    const int j   = jt * 16 + cl;

    // ---- A frags (all 8 ksub upfront: max memory-level parallelism) ----
    bf16x8 fAh[8], fAl[8];
    const size_t ab = (size_t)(m0 + cl) * 256 + ch * 8;
    #pragma unroll
    for (int ks = 0; ks < 8; ++ks) {
        fAh[ks] = *(const bf16x8*)(hhi_in + ab + ks * 32);
        fAl[ks] = *(const bf16x8*)(hlo_in + ab + ks * 32);
    }

    // ---- G + c (lane-local epilogue operands; independent of GEMM) ----
    float Ge[4][4];                    // [gate][r]
    const float* Gb = G + ((size_t)(rnn * CH + sl) * B_ + b0 + ch * 4) * G4H + jt * 64;
    #pragma unroll
    for (int r = 0; r < 4; ++r)
        #pragma unroll
        for (int g = 0; g < 4; ++g)
            Ge[g][r] = Gb[(size_t)r * G4H + g * 16 + cl];
    float c_in[4];
    #pragma unroll
    for (int r = 0; r < 4; ++r)
        c_in[r] = first ? 0.f : cst[(size_t)(m0 + ch * 4 + r) * 256 + j];

    // ---- MFMA: 8 ksub x (4 gates x 3 passes), 4 independent chains ----
    f32x4 acc[4];
    #pragma unroll
    for (int g = 0; g < 4; ++g) acc[g] = (f32x4){0.f, 0.f, 0.f, 0.f};

    #pragma unroll
    for (int ks = 0; ks < 8; ++ks) {
        bf16x8 fBh[4], fBl[4];
        #pragma unroll
        for (int g = 0; g < 4; ++g) {
            const size_t bb = (size_t)(jt * 64 + g * 16 + cl) * 256 + ks * 32 + ch * 8;
            fBh[g] = *(const bf16x8*)(Whi + bb);
            fBl[g] = *(const bf16x8*)(Wlo + bb);
        }
        #pragma unroll
        for (int g = 0; g < 4; ++g)
            acc[g] = __builtin_amdgcn_mfma_f32_16x16x32_bf16(fAh[ks], fBh[g], acc[g], 0, 0, 0);
        #pragma unroll
        for (int g = 0; g < 4; ++g)
            acc[g] = __builtin_amdgcn_mfma_f32_16x16x32_bf16(fAh[ks], fBl[g], acc[g], 0, 0, 0);
        #pragma unroll
        for (int g = 0; g < 4; ++g)
            acc[g] = __builtin_amdgcn_mfma_f32_16x16x32_bf16(fAl[ks], fBh[g], acc[g], 0, 0, 0);
    }

    // ---- lane-local gate math + state update (no barriers anywhere) ----
    #pragma unroll
    for (int r = 0; r < 4; ++r) {
        const float gi = acc[0][r] + Ge[0][r];
        const float gf = acc[1][r] + Ge[1][r];
        const float gg = acc[2][r] + Ge[2][r];
        const float go = acc[3][r] + Ge[3][r];
        const float c = sigf(gf) * c_in[r] + sigf(gi) * tanhf(gg);
        const float h = sigf(go) * tanhf(c);
        cst[(size_t)(m0 + ch * 4 + r) * 256 + j] = c;
        const __bf16 hh = (__bf16)h;
        const size_t ho = (size_t)(m0 + ch * 4 + r) * 256 + j;
        hhi_out[ho] = hh;
        hlo_out[ho] = (__bf16)(h - (float)hh);
        if (rnn == 0)
            sc[((size_t)(b0 + ch * 4 + r) * S_ + s_glob) * H_ + j] = h;
    }
}

// ---------------------------------------------------------------------------
// Fused attention epilogue, one block per batch row b. r reconstructed from
// final h hi/lo planes (rnn1 rows = 256..511).
// ---------------------------------------------------------------------------
__global__ __launch_bounds__(256) void final_kernel(
    const float* __restrict__ sc,
    const __bf16* __restrict__ rhi, const __bf16* __restrict__ rlo,
    const float* __restrict__ Wattn, const float* __restrict__ battn,
    const float* __restrict__ M, const float* __restrict__ bscal,
    const float* __restrict__ mask, float* __restrict__ out)
{
    __shared__ float rs[256], us[256], red[256], as_[256];
    const int b = blockIdx.x;
    const int t = threadIdx.x;

    const size_t ri = (size_t)(256 + b) * 256 + t;
    rs[t] = (float)rhi[ri] + (float)rlo[ri];
    __syncthreads();

    float acc = 0.0f;
    for (int h = 0; h < 256; ++h) acc += rs[h] * Wattn[h * 256 + t];
    us[t] = acc;

    red[t] = battn[t] * rs[t];
    __syncthreads();
    for (int off = 128; off; off >>= 1) {
        if (t < off) red[t] += red[t + off];
        __syncthreads();
    }
    float beta = red[0];
    __syncthreads();

    float vh = 0.0f;
    {
        const float* Mrow = M + t * 256;
        for (int k = 0; k < 256; ++k) vh += Mrow[k] * rs[k];
    }

    float e = -INFINITY;
    if (t < S_) {
        float d = 0.0f;
        const float* scrow = sc + ((size_t)b * S_ + t) * H_;
        for (int h = 0; h < 256; ++h) d += scrow[h] * us[h];
        e = (d + beta) * mask[b * S_ + t];
    }
    red[t] = e;
    __syncthreads();
    for (int off = 128; off; off >>= 1) {
        if (t < off) red[t] = fmaxf(red[t], red[t + off]);
        __syncthreads();
    }
    float mx = red[0];
    __syncthreads();

    float p = (t < S_) ? expf(e - mx) : 0.0f;
    as_[t] = p;
    red[t] = p;
    __syncthreads();
    for (int off = 128; off; off >>= 1) {
        if (t < off) red[t] += red[t + off];
        __syncthreads();
    }
    float inv = 1.0f / red[0];
    __syncthreads();

    float ca = 0.0f;
    for (int s = 0; s < S_; ++s) ca += as_[s] * sc[((size_t)b * S_ + s) * H_ + t];
    ca *= inv;

    red[t] = ca * vh;
    __syncthreads();
    for (int off = 128; off; off >>= 1) {
        if (t < off) red[t] += red[t + off];
        __syncthreads();
    }
    if (t == 0) out[b] = red[0] + bscal[0];
}

// ---------------------------------------------------------------------------
extern "C" void kernel_launch(void* const* d_in, const int* in_sizes, int n_in,
                              void* d_out, int out_size, void* d_ws, size_t ws_size,
                              hipStream_t stream)
{
    const int*   x1    = (const int*)d_in[0];
    const int*   x2    = (const int*)d_in[1];
    const float* mask  = (const float*)d_in[2];
    const float* key_c = (const float*)d_in[3];
    const float* key_r = (const float*)d_in[4];
    const float* emb   = (const float*)d_in[5];
    const float* Wih   = (const float*)d_in[6];
    const float* Whh   = (const float*)d_in[7];
    const float* Wkh   = (const float*)d_in[8];
    const float* bg    = (const float*)d_in[9];
    const float* Wattn = (const float*)d_in[10];
    const float* battn = (const float*)d_in[11];
    const float* M     = (const float*)d_in[12];
    const float* bb    = (const float*)d_in[13];
    float* out = (float*)d_out;
    char*  wsb = (char*)d_ws;

    // byte layout
    float*  G     = (float*)(wsb + 0);            // 33,554,432
    float*  sc    = (float*)(wsb + 33554432);     // 41,943,040
    __bf16* hhi0  = (__bf16*)(wsb + 75497472);    //    262,144
    __bf16* hlo0  = (__bf16*)(wsb + 75759616);    //    262,144
    __bf16* hhi1  = (__bf16*)(wsb + 76021760);    //    262,144
    __bf16* hlo1  = (__bf16*)(wsb + 76283904);    //    262,144
    float*  cst   = (float*)(wsb + 76546048);     //    524,288
    __bf16* WhhHi = (__bf16*)(wsb + 77070336);    //    524,288
    __bf16* WhhLo = (__bf16*)(wsb + 77594624);    //    524,288
    __bf16* WikHi = (__bf16*)(wsb + 78118912);    //  1,048,576
    __bf16* WikLo = (__bf16*)(wsb + 79167488);    //  1,048,576
    if (ws_size < 80216064) return;  // fail visibly if workspace too small

    // zero parity-0 h planes (hhi0+hlo0 contiguous)
    hipMemsetAsync(hhi0, 0, 524288, stream);
    prep_split<<<dim3(1024), 128, 0, stream>>>(Whh, Wih, Wkh,
                                               WhhHi, WhhLo, WikHi, WikLo);

    for (int ci = 0; ci < NCH; ++ci) {
        gemm_g2<<<dim3(32, 8, 2), 512, 0, stream>>>(x1, x2, key_c, key_r, emb,
                                                    WikHi, WikLo, bg, G, ci * CH);
        for (int slq = 0; slq < CH; ++slq) {
            const int s   = ci * CH + slq;
            const int par = s & 1;
            lstm_dir<<<dim3(512), 64, 0, stream>>>(G, WhhHi, WhhLo,
                                                   par ? hhi1 : hhi0,
                                                   par ? hlo1 : hlo0,
                                                   par ? hhi0 : hhi1,
                                                   par ? hlo0 : hlo1,
                                                   cst, sc, slq, s, s == 0);
        }
    }

    // 160 steps (even) -> final h in plane 0; r = rnn1 rows
    final_kernel<<<dim3(256), 256, 0, stream>>>(sc, hhi0, hlo0, Wattn, battn,
                                                M, bb, mask, out);
}

// Round 12
// 1473.288 us; speedup vs baseline: 1.2905x; 1.2905x over previous
//
#include <hip/hip_runtime.h>
#include <math.h>

#define B_   256
#define S_   160
#define E_   300
#define H_   256
#define T_   200
#define G4H  1024
#define CH   16
#define NCH  10

typedef float  f32x4  __attribute__((ext_vector_type(4)));
typedef __bf16 bf16x4 __attribute__((ext_vector_type(4)));
typedef __bf16 bf16x8 __attribute__((ext_vector_type(8)));

__device__ __forceinline__ float sigf(float x) {
    float e = expf(-fabsf(x));
    float p = 1.0f / (1.0f + e);
    return x >= 0.0f ? p : e * p;
}

// permuted gate-col order: n' = (j>>4)*64 + g*16 + (j&15); orig row for n':
__device__ __forceinline__ int norig(int np) {
    return ((np >> 4) & 3) * 256 + ((np >> 6) << 4) + (np & 15);
}

// 4 consecutive K-values from concatenated [first(300) | second(200) | pad] row
__device__ __forceinline__ float4 pick4(const float* __restrict__ e,
                                        const float* __restrict__ k, int kg) {
    if (kg < E_)      return *(const float4*)(e + kg);
    if (kg < E_ + T_) return *(const float4*)(k + (kg - E_));
    return make_float4(0.f, 0.f, 0.f, 0.f);
}

__device__ __forceinline__ void split4(float4 v, bf16x4& h, bf16x4& l) {
    h[0] = (__bf16)v.x; l[0] = (__bf16)(v.x - (float)h[0]);
    h[1] = (__bf16)v.y; l[1] = (__bf16)(v.y - (float)h[1]);
    h[2] = (__bf16)v.z; l[2] = (__bf16)(v.z - (float)h[2]);
    h[3] = (__bf16)v.w; l[3] = (__bf16)(v.w - (float)h[3]);
}

// ---------------------------------------------------------------------------
// One-time weight prep: rows in permuted n' order, bf16 hi/lo planes.
// ---------------------------------------------------------------------------
__global__ __launch_bounds__(128) void prep_split(
    const float* __restrict__ Whh, const float* __restrict__ Wih,
    const float* __restrict__ Wkh,
    __bf16* __restrict__ whh_hi, __bf16* __restrict__ whh_lo,
    __bf16* __restrict__ wik_hi, __bf16* __restrict__ wik_lo)
{
    const int n  = blockIdx.x;                         // orig row: g*256 + j
    const int np = ((n & 255) >> 4) * 64 + (n >> 8) * 16 + (n & 15);
    const int t  = threadIdx.x;
    {
        const int k4 = t * 4;
        float4 v;
        if (k4 < E_)            v = *(const float4*)(Wih + (size_t)n * E_ + k4);
        else if (k4 < E_ + T_)  v = *(const float4*)(Wkh + (size_t)n * T_ + (k4 - E_));
        else                    v = make_float4(0.f, 0.f, 0.f, 0.f);
        bf16x4 h, l;
        split4(v, h, l);
        *(bf16x4*)(wik_hi + (size_t)np * 512 + k4) = h;
        *(bf16x4*)(wik_lo + (size_t)np * 512 + k4) = l;
    }
    if (t < 64) {
        const int k4 = t * 4;
        const float4 v = *(const float4*)(Whh + (size_t)n * 256 + k4);
        bf16x4 h, l;
        split4(v, h, l);
        *(bf16x4*)(whh_hi + (size_t)np * 256 + k4) = h;
        *(bf16x4*)(whh_lo + (size_t)np * 256 + k4) = l;
    }
}

// ---------------------------------------------------------------------------
// Input GEMM (r10-proven: 46us, 0 conflicts): split-bf16 MFMA, tile 128x128,
// BK=32, 512 threads = 8 waves (wave tile 64x32). 2 blocks/CU.
// ---------------------------------------------------------------------------
__global__ __launch_bounds__(512, 2) void gemm_g2(
    const int* __restrict__ x1, const int* __restrict__ x2,
    const float* __restrict__ key_c, const float* __restrict__ key_r,
    const float* __restrict__ emb,
    const __bf16* __restrict__ wik_hi, const __bf16* __restrict__ wik_lo,
    const float* __restrict__ bg,
    float* __restrict__ G, int s0)
{
    __shared__ __align__(16) __bf16 Ah[128 * 32];
    __shared__ __align__(16) __bf16 Al[128 * 32];
    __shared__ __align__(16) __bf16 Bh[128 * 32];
    __shared__ __align__(16) __bf16 Bl[128 * 32];

    const int t   = threadIdx.x;
    const int rnn = blockIdx.z;
    const int m0  = blockIdx.x * 128;
    const int n0  = blockIdx.y * 128;
    const int* xx = rnn ? x2 : x1;
    const float* key = rnn ? key_r : key_c;

    // staging: row r0 = t>>2 (0..127), 16B chunk pair cq = t&3 (k = cq*8..cq*8+7)
    const int r0 = t >> 2;
    const int cq = t & 3;
    const int csw = ((cq ^ ((r0 >> 1) & 3)) * 16);   // swizzled 16B chunk offset

    const float* aeb; const float* akb;
    const __bf16* wph; const __bf16* wpl;
    {
        const int am = m0 + r0;
        const int bs = (am >> 4) * S_ + s0 + (am & 15);
        aeb = emb + (size_t)xx[bs] * E_;
        akb = key + (size_t)bs * T_;
        wph = wik_hi + (size_t)(n0 + r0) * 512;
        wpl = wik_lo + (size_t)(n0 + r0) * 512;
    }

    const int w  = t >> 6;       // 0..7
    const int wm = w >> 2;       // 0..1  (64-row half)
    const int wn = w & 3;        // 0..3  (32-col quarter)
    const int l  = t & 63;
    const int cl = l & 15;
    const int ch = l >> 4;
    const int chs = ((ch ^ ((cl >> 1) & 3)) * 16);

    f32x4 acc[4][2];
    #pragma unroll
    for (int fm = 0; fm < 4; ++fm)
        #pragma unroll
        for (int fn = 0; fn < 2; ++fn) acc[fm][fn] = (f32x4){0.f, 0.f, 0.f, 0.f};

    for (int kt = 0; kt < 16; ++kt) {
        const int kg = kt * 32 + cq * 8;
        const float4 va0 = pick4(aeb, akb, kg);
        const float4 va1 = pick4(aeb, akb, kg + 4);
        const bf16x8 vbh = *(const bf16x8*)(wph + kg);
        const bf16x8 vbl = *(const bf16x8*)(wpl + kg);
        bf16x4 h0, l0, h1, l1;
        split4(va0, h0, l0);
        split4(va1, h1, l1);
        const bf16x8 sah = __builtin_shufflevector(h0, h1, 0, 1, 2, 3, 4, 5, 6, 7);
        const bf16x8 sal = __builtin_shufflevector(l0, l1, 0, 1, 2, 3, 4, 5, 6, 7);
        __syncthreads();
        {
            const int off = r0 * 64 + csw;
            *(bf16x8*)((char*)Ah + off) = sah;
            *(bf16x8*)((char*)Al + off) = sal;
            *(bf16x8*)((char*)Bh + off) = vbh;
            *(bf16x8*)((char*)Bl + off) = vbl;
        }
        __syncthreads();

        bf16x8 fBh[2], fBl[2];
        #pragma unroll
        for (int fn = 0; fn < 2; ++fn) {
            const int off = (wn * 32 + fn * 16 + cl) * 64 + chs;
            fBh[fn] = *(const bf16x8*)((const char*)Bh + off);
            fBl[fn] = *(const bf16x8*)((const char*)Bl + off);
        }
        #pragma unroll
        for (int fm = 0; fm < 4; ++fm) {
            const int off = (wm * 64 + fm * 16 + cl) * 64 + chs;
            const bf16x8 fAh = *(const bf16x8*)((const char*)Ah + off);
            const bf16x8 fAl = *(const bf16x8*)((const char*)Al + off);
            #pragma unroll
            for (int fn = 0; fn < 2; ++fn) {
                acc[fm][fn] = __builtin_amdgcn_mfma_f32_16x16x32_bf16(fAh, fBh[fn], acc[fm][fn], 0, 0, 0);
                acc[fm][fn] = __builtin_amdgcn_mfma_f32_16x16x32_bf16(fAh, fBl[fn], acc[fm][fn], 0, 0, 0);
                acc[fm][fn] = __builtin_amdgcn_mfma_f32_16x16x32_bf16(fAl, fBh[fn], acc[fm][fn], 0, 0, 0);
            }
        }
    }

    float bgl[2];
    #pragma unroll
    for (int fn = 0; fn < 2; ++fn)
        bgl[fn] = bg[norig(n0 + wn * 32 + fn * 16 + cl)];

    #pragma unroll
    for (int fm = 0; fm < 4; ++fm) {
        #pragma unroll
        for (int r = 0; r < 4; ++r) {
            const int m  = m0 + wm * 64 + fm * 16 + ch * 4 + r;
            const int b  = m >> 4;
            const int sl = m & 15;
            float* rowp = G + ((size_t)(rnn * CH + sl) * B_ + b) * G4H;
            #pragma unroll
            for (int fn = 0; fn < 2; ++fn)
                rowp[n0 + wn * 32 + fn * 16 + cl] = acc[fm][fn][r] + bgl[fn];
        }
    }
}

// ---------------------------------------------------------------------------
// One LSTM step, K-split x4 (r9-proven: ~6.0us/step wall). Grid (32 mt,
// 16 jt) = 512 blocks x 256 thr (4 waves) = 8 waves/CU. Wave w: K-slice
// [w*64, w*64+64) of the 16m x 64n' tile -> 24 MFMA; partials reduced via
// LDS; gate math lane-local (n' permutation); h = bf16 hi/lo planes.
// ---------------------------------------------------------------------------
__global__ __launch_bounds__(256, 2) void lstm_ks(
    const float* __restrict__ G,
    const __bf16* __restrict__ Whi, const __bf16* __restrict__ Wlo,
    const __bf16* __restrict__ hhi_in, const __bf16* __restrict__ hlo_in,
    __bf16* __restrict__ hhi_out, __bf16* __restrict__ hlo_out,
    float* __restrict__ cst, float* __restrict__ sc,
    int sl, int s_glob, int first)
{
    __shared__ float ps[64 * 66];      // 16.9 KB

    const int t  = threadIdx.x;
    const int w  = t >> 6;
    const int l  = t & 63;
    const int cl = l & 15;
    const int ch = l >> 4;
    const int mt = blockIdx.x;         // 0..31
    const int jt = blockIdx.y;         // 0..15
    const int rnn = mt >> 4;
    const int b0  = (mt & 15) * 16;
    const int m0  = mt * 16;           // plane row base (= rnn*256 + b0)

    // ---- epilogue operands (independent; issue at entry) ----
    const int me = t >> 4;             // 0..15
    const int jl = t & 15;
    const int j  = jt * 16 + jl;
    float Ge[4];
    const float* Gb = G + ((size_t)(rnn * CH + sl) * B_ + b0 + me) * G4H + jt * 64;
    #pragma unroll
    for (int g = 0; g < 4; ++g) Ge[g] = Gb[g * 16 + jl];
    const float c_in = first ? 0.f : cst[(size_t)(m0 + me) * 256 + j];

    // ---- A frags (this wave's K-slice: ks = 2w, 2w+1) ----
    const size_t ab = (size_t)(m0 + cl) * 256 + w * 64 + ch * 8;
    const bf16x8 fAh0 = *(const bf16x8*)(hhi_in + ab);
    const bf16x8 fAh1 = *(const bf16x8*)(hhi_in + ab + 32);
    const bf16x8 fAl0 = *(const bf16x8*)(hlo_in + ab);
    const bf16x8 fAl1 = *(const bf16x8*)(hlo_in + ab + 32);

    // ---- B frags ----
    bf16x8 fBh[4][2], fBl[4][2];
    #pragma unroll
    for (int g = 0; g < 4; ++g) {
        const size_t bb = (size_t)(jt * 64 + g * 16 + cl) * 256 + w * 64 + ch * 8;
        fBh[g][0] = *(const bf16x8*)(Whi + bb);
        fBh[g][1] = *(const bf16x8*)(Whi + bb + 32);
        fBl[g][0] = *(const bf16x8*)(Wlo + bb);
        fBl[g][1] = *(const bf16x8*)(Wlo + bb + 32);
    }

    f32x4 acc[4];
    #pragma unroll
    for (int g = 0; g < 4; ++g) acc[g] = (f32x4){0.f, 0.f, 0.f, 0.f};
    #pragma unroll
    for (int g = 0; g < 4; ++g) {
        acc[g] = __builtin_amdgcn_mfma_f32_16x16x32_bf16(fAh0, fBh[g][0], acc[g], 0, 0, 0);
        acc[g] = __builtin_amdgcn_mfma_f32_16x16x32_bf16(fAh1, fBh[g][1], acc[g], 0, 0, 0);
        acc[g] = __builtin_amdgcn_mfma_f32_16x16x32_bf16(fAh0, fBl[g][0], acc[g], 0, 0, 0);
        acc[g] = __builtin_amdgcn_mfma_f32_16x16x32_bf16(fAh1, fBl[g][1], acc[g], 0, 0, 0);
        acc[g] = __builtin_amdgcn_mfma_f32_16x16x32_bf16(fAl0, fBh[g][0], acc[g], 0, 0, 0);
        acc[g] = __builtin_amdgcn_mfma_f32_16x16x32_bf16(fAl1, fBh[g][1], acc[g], 0, 0, 0);
    }

    // ---- psum to LDS ----
    #pragma unroll
    for (int g = 0; g < 4; ++g)
        #pragma unroll
        for (int r = 0; r < 4; ++r)
            ps[(w * 16 + ch * 4 + r) * 66 + g * 16 + cl] = acc[g][r];
    __syncthreads();

    // ---- reduce 4 K-slices + gate math (1 cell/thread) ----
    float g4[4];
    #pragma unroll
    for (int g = 0; g < 4; ++g) {
        float s = Ge[g];
        #pragma unroll
        for (int w2 = 0; w2 < 4; ++w2)
            s += ps[(w2 * 16 + me) * 66 + g * 16 + jl];
        g4[g] = s;
    }
    const float c = sigf(g4[1]) * c_in + sigf(g4[0]) * tanhf(g4[2]);
    const float h = sigf(g4[3]) * tanhf(c);
    cst[(size_t)(m0 + me) * 256 + j] = c;
    const __bf16 hh = (__bf16)h;
    const size_t ho = (size_t)(m0 + me) * 256 + j;
    hhi_out[ho] = hh;
    hlo_out[ho] = (__bf16)(h - (float)hh);
    if (rnn == 0)
        sc[((size_t)(b0 + me) * S_ + s_glob) * H_ + j] = h;
}

// ---------------------------------------------------------------------------
// Fused attention epilogue, one block per batch row b. r reconstructed from
// final h hi/lo planes (rnn1 rows = 256..511).
// ---------------------------------------------------------------------------
__global__ __launch_bounds__(256) void final_kernel(
    const float* __restrict__ sc,
    const __bf16* __restrict__ rhi, const __bf16* __restrict__ rlo,
    const float* __restrict__ Wattn, const float* __restrict__ battn,
    const float* __restrict__ M, const float* __restrict__ bscal,
    const float* __restrict__ mask, float* __restrict__ out)
{
    __shared__ float rs[256], us[256], red[256], as_[256];
    const int b = blockIdx.x;
    const int t = threadIdx.x;

    const size_t ri = (size_t)(256 + b) * 256 + t;
    rs[t] = (float)rhi[ri] + (float)rlo[ri];
    __syncthreads();

    float acc = 0.0f;
    for (int h = 0; h < 256; ++h) acc += rs[h] * Wattn[h * 256 + t];
    us[t] = acc;

    red[t] = battn[t] * rs[t];
    __syncthreads();
    for (int off = 128; off; off >>= 1) {
        if (t < off) red[t] += red[t + off];
        __syncthreads();
    }
    float beta = red[0];
    __syncthreads();

    float vh = 0.0f;
    {
        const float* Mrow = M + t * 256;
        for (int k = 0; k < 256; ++k) vh += Mrow[k] * rs[k];
    }

    float e = -INFINITY;
    if (t < S_) {
        float d = 0.0f;
        const float* scrow = sc + ((size_t)b * S_ + t) * H_;
        for (int h = 0; h < 256; ++h) d += scrow[h] * us[h];
        e = (d + beta) * mask[b * S_ + t];
    }
    red[t] = e;
    __syncthreads();
    for (int off = 128; off; off >>= 1) {
        if (t < off) red[t] = fmaxf(red[t], red[t + off]);
        __syncthreads();
    }
    float mx = red[0];
    __syncthreads();

    float p = (t < S_) ? expf(e - mx) : 0.0f;
    as_[t] = p;
    red[t] = p;
    __syncthreads();
    for (int off = 128; off; off >>= 1) {
        if (t < off) red[t] += red[t + off];
        __syncthreads();
    }
    float inv = 1.0f / red[0];
    __syncthreads();

    float ca = 0.0f;
    for (int s = 0; s < S_; ++s) ca += as_[s] * sc[((size_t)b * S_ + s) * H_ + t];
    ca *= inv;

    red[t] = ca * vh;
    __syncthreads();
    for (int off = 128; off; off >>= 1) {
        if (t < off) red[t] += red[t + off];
        __syncthreads();
    }
    if (t == 0) out[b] = red[0] + bscal[0];
}

// ---------------------------------------------------------------------------
extern "C" void kernel_launch(void* const* d_in, const int* in_sizes, int n_in,
                              void* d_out, int out_size, void* d_ws, size_t ws_size,
                              hipStream_t stream)
{
    const int*   x1    = (const int*)d_in[0];
    const int*   x2    = (const int*)d_in[1];
    const float* mask  = (const float*)d_in[2];
    const float* key_c = (const float*)d_in[3];
    const float* key_r = (const float*)d_in[4];
    const float* emb   = (const float*)d_in[5];
    const float* Wih   = (const float*)d_in[6];
    const float* Whh   = (const float*)d_in[7];
    const float* Wkh   = (const float*)d_in[8];
    const float* bg    = (const float*)d_in[9];
    const float* Wattn = (const float*)d_in[10];
    const float* battn = (const float*)d_in[11];
    const float* M     = (const float*)d_in[12];
    const float* bb    = (const float*)d_in[13];
    float* out = (float*)d_out;
    char*  wsb = (char*)d_ws;

    // byte layout
    float*  G     = (float*)(wsb + 0);            // 33,554,432
    float*  sc    = (float*)(wsb + 33554432);     // 41,943,040
    __bf16* hhi0  = (__bf16*)(wsb + 75497472);    //    262,144
    __bf16* hlo0  = (__bf16*)(wsb + 75759616);    //    262,144
    __bf16* hhi1  = (__bf16*)(wsb + 76021760);    //    262,144
    __bf16* hlo1  = (__bf16*)(wsb + 76283904);    //    262,144
    float*  cst   = (float*)(wsb + 76546048);     //    524,288
    __bf16* WhhHi = (__bf16*)(wsb + 77070336);    //    524,288
    __bf16* WhhLo = (__bf16*)(wsb + 77594624);    //    524,288
    __bf16* WikHi = (__bf16*)(wsb + 78118912);    //  1,048,576
    __bf16* WikLo = (__bf16*)(wsb + 79167488);    //  1,048,576
    if (ws_size < 80216064) return;  // fail visibly if workspace too small

    // zero parity-0 h planes (hhi0+hlo0 contiguous)
    hipMemsetAsync(hhi0, 0, 524288, stream);
    prep_split<<<dim3(1024), 128, 0, stream>>>(Whh, Wih, Wkh,
                                               WhhHi, WhhLo, WikHi, WikLo);

    for (int ci = 0; ci < NCH; ++ci) {
        gemm_g2<<<dim3(32, 8, 2), 512, 0, stream>>>(x1, x2, key_c, key_r, emb,
                                                    WikHi, WikLo, bg, G, ci * CH);
        for (int slq = 0; slq < CH; ++slq) {
            const int s   = ci * CH + slq;
            const int par = s & 1;
            lstm_ks<<<dim3(32, 16), 256, 0, stream>>>(G, WhhHi, WhhLo,
                                                      par ? hhi1 : hhi0,
                                                      par ? hlo1 : hlo0,
                                                      par ? hhi0 : hhi1,
                                                      par ? hlo0 : hlo1,
                                                      cst, sc, slq, s, s == 0);
        }
    }

    // 160 steps (even) -> final h in plane 0; r = rnn1 rows
    final_kernel<<<dim3(256), 256, 0, stream>>>(sc, hhi0, hlo0, Wattn, battn,
                                                M, bb, mask, out);
}